// Round 16
// baseline (453.042 us; speedup 1.0000x reference)
//
#include <hip/hip_runtime.h>
#include <hip/hip_bf16.h>

// ModernNCA fused pipeline for MI355X (gfx950). Round 18: 8-deep in-tile c
// ring in dist (latency halving WITHOUT crossing the epilogue).
//
// R17 post-mortem: total 347.5us (best). dist reverted clean (168us, FETCH
// 63MB); encode restructure -> out of top-5. dist still latency-bound: MFMA
// waits on the load issued 4 iters ago (~L/4 = 75-100cyc/iter vs 16cyc MFMA
// -> MfmaUtil 32%). R15/R16 spilled because br lived ACROSS the epilogue.
// R18: ring 4 -> 8 deep, fully inside the tile: prologue 8 loads; ks0..23
// load ks+8; ks24..31 drain. br dead at tile end -> no overlap with bf-build
// ya..yd peak. K-loop arch: br 32 + a0/a1 8 + bn 4 + addr ~15 = ~59 <= 64.
// Spill tripwire: FETCH > 80MB -> revert to 4-deep.
//
// Padding: 5000->5120 per chunk; pad rows c=0, csq=1e4 -> d>=100 -> ed==0;
// each pad adds exp(0)=1 to chunk sumexp; finalize subtracts 120.

typedef _Float16 f16x8 __attribute__((ext_vector_type(8)));
typedef _Float16 f16x4 __attribute__((ext_vector_type(4)));
typedef __fp16 fp16x2r __attribute__((ext_vector_type(2)));  // cvt_pkrtz ret type
typedef float f32x4 __attribute__((ext_vector_type(4)));
typedef float f32x16 __attribute__((ext_vector_type(16)));

#define MFMA16(a, b, c) __builtin_amdgcn_mfma_f32_16x16x32_f16(a, b, c, 0, 0, 0)
#define MFMA32(a, b, c) __builtin_amdgcn_mfma_f32_32x32x16_f16(a, b, c, 0, 0, 0)

// pack two f32 -> one u32 of 2 f16 (RTZ)
static __device__ __forceinline__ unsigned pkh(float a, float b) {
  union { fp16x2r h; unsigned u; } x;
  x.h = __builtin_amdgcn_cvt_pkrtz(a, b);
  return x.u;
}

static __device__ __forceinline__ f16x8 mk8(unsigned a, unsigned b, unsigned c,
                                            unsigned d) {
  union { unsigned u[4]; f16x8 v; } x;
  x.u[0] = a; x.u[1] = b; x.u[2] = c; x.u[3] = d;
  return x.v;
}

// v_permlane32_swap_b32 a, b : exchanges a.hi(lanes32-63) <-> b.lo(lanes0-31)
#define PLSWAP(a, b) asm("v_permlane32_swap_b32 %0, %1" : "+v"(a), "+v"(b))

// ---------------- prep: fragment-packed W1t/W2t, padded y, zero accumulators
// Weight fragment packing: for A-frag at (n-tile nt, k-tile kt), lane
// l = quad*16 + l15 holds row nt*16+l15, cols kt*32+quad*8..+8. Stored as one
// 1KB block: halfword dst = (nt*KT+kt)*512 + l*8 + e.
__global__ __launch_bounds__(256) void prep_kernel(
    const float* __restrict__ W1, const float* __restrict__ W2,
    const int* __restrict__ y, _Float16* __restrict__ w1t,
    _Float16* __restrict__ w2t, int* __restrict__ ypad,
    float* __restrict__ zero_base) {
  int idx = blockIdx.x * 256 + threadIdx.x;
  if (idx < 49152) {                       // W1 [96,512] -> packed [32][3][1KB]
    int n = idx / 96, k = idx - n * 96;
    int nt = n >> 4, l15 = n & 15;
    int kt = k >> 5, kr = k & 31, quad = kr >> 3, e = kr & 7;
    int lane = quad * 16 + l15;
    w1t[(nt * 3 + kt) * 512 + lane * 8 + e] = (_Float16)W1[k * 512 + n];
  } else if (idx < 311296) {               // W2 [512,512] -> packed [32][16][1KB]
    int j = idx - 49152;
    int n = j / 512, k = j - n * 512;
    int nt = n >> 4, l15 = n & 15;
    int kt = k >> 5, kr = k & 31, quad = kr >> 3, e = kr & 7;
    int lane = quad * 16 + l15;
    w2t[(nt * 16 + kt) * 512 + lane * 8 + e] = (_Float16)W2[k * 512 + n];
  } else if (idx < 413696) {               // padded candidate_y
    int j = idx - 311296;
    int ch = j / 5120, pos = j - ch * 5120;
    ypad[j] = (pos < 5000) ? y[ch * 5000 + pos] : 0;
  } else if (idx < 619520) {
    // zero: csq(102400) qsq(1024) sumexp(20480) lgts_part(81920) = 205824 f32
    zero_base[idx - 413696] = 0.0f;
  }
}

// ---------------- fused 2-layer encoder: enc = relu(x@W1+b1)@W2 + b2
// One launch covers BOTH inputs: blocks [0,16) = query rows (1024, no chunk
// padding), blocks [16,1616) = candidate rows (5000->5120 chunked). Mode is
// block-uniform; each path keeps its compile-time constants.
// 512 threads / 8 waves; each wave owns 64 output cols (4 n-tiles) -> acc =
// 64 AGPR; (512,4) pins 64 arch + 64 acc = 128 unified -> 4 waves/SIMD,
// LDS 80KB -> 2 blocks/CU -> 16 waves/CU.
// Output written in MFMA-fragment-packed layout; weights read fragment-packed.
__global__ __launch_bounds__(512, 4) void encode_kernel(
    const float* __restrict__ xn_c, const float* __restrict__ xc_c,
    const float* __restrict__ xn_q, const float* __restrict__ xc_q,
    const _Float16* __restrict__ w1t, const float* __restrict__ b1,
    const _Float16* __restrict__ w2t, const float* __restrict__ b2,
    _Float16* __restrict__ out_c, float* __restrict__ csq,
    _Float16* __restrict__ out_q, float* __restrict__ qsq) {
  __shared__ __align__(16) char lds_x[16384];  // 64 rows x 16 units(16B) swz
  __shared__ __align__(16) char lds_h[65536];  // 64 rows x 64 units(16B) swz

  const int t = threadIdx.x;
  const bool qm = blockIdx.x < 16;
  const int R0 = (qm ? blockIdx.x : blockIdx.x - 16) * 64;
  const float* xn = qm ? xn_q : xn_c;
  const float* xc = qm ? xc_q : xc_c;
  _Float16* out = qm ? out_q : out_c;
  float* outsq = qm ? qsq : csq;

  const int w = t >> 6, l = t & 63;          // w in [0,8)
  const int l15 = l & 15, quad = l >> 4;
  const int ncol0 = w * 64;                  // 64 cols per wave

#pragma unroll
  for (int it = 0; it < 2; it++) {
    int idx = it * 512 + t;
    int row = idx >> 4, kq = idx & 15;
    int pr = R0 + row;
    int orig;
    bool rowvalid;
    if (qm) {
      orig = pr; rowvalid = true;
    } else {
      int ch = pr / 5120, pos = pr - ch * 5120;
      rowvalid = pos < 5000;
      orig = ch * 5000 + pos;
    }
    float v[8] = {0, 0, 0, 0, 0, 0, 0, 0};
    if (rowvalid && kq < 12) {
      float4 f0, f1;
      if (kq < 8) {
        f0 = *(const float4*)&xn[orig * 64 + kq * 8];
        f1 = *(const float4*)&xn[orig * 64 + kq * 8 + 4];
      } else {
        f0 = *(const float4*)&xc[orig * 32 + (kq - 8) * 8];
        f1 = *(const float4*)&xc[orig * 32 + (kq - 8) * 8 + 4];
      }
      v[0] = f0.x; v[1] = f0.y; v[2] = f0.z; v[3] = f0.w;
      v[4] = f1.x; v[5] = f1.y; v[6] = f1.z; v[7] = f1.w;
    }
    f16x8 hv;
#pragma unroll
    for (int j = 0; j < 8; j++) hv[j] = (_Float16)v[j];
    *(f16x8*)&lds_x[row * 256 + (((kq ^ (row & 7)) & 15) << 4)] = hv;
  }
  __syncthreads();

  f32x4 acc1[4][4];
#pragma unroll
  for (int ni = 0; ni < 4; ni++)
#pragma unroll
    for (int rt = 0; rt < 4; rt++) acc1[ni][rt] = (f32x4)(0.0f);

#pragma unroll
  for (int kt = 0; kt < 3; kt++) {
    f16x8 bx[4];
#pragma unroll
    for (int rt = 0; rt < 4; rt++) {
      int row = rt * 16 + l15;
      int kq = kt * 4 + quad;
      bx[rt] = *(const f16x8*)&lds_x[row * 256 + (((kq ^ (row & 7)) & 15) << 4)];
    }
#pragma unroll
    for (int ni = 0; ni < 4; ni++) {
      f16x8 aw = *(const f16x8*)&w1t[((w * 4 + ni) * 3 + kt) * 512 + l * 8];
#pragma unroll
      for (int rt = 0; rt < 4; rt++) acc1[ni][rt] = MFMA16(aw, bx[rt], acc1[ni][rt]);
    }
  }

#pragma unroll
  for (int ni = 0; ni < 4; ni++) {
    float4 b1v = *(const float4*)&b1[ncol0 + ni * 16 + quad * 4];
    int kq2 = (ncol0 >> 3) + ni * 2 + (quad >> 1);
#pragma unroll
    for (int rt = 0; rt < 4; rt++) {
      int row = rt * 16 + l15;
      f16x4 hv;
      hv[0] = (_Float16)fmaxf(acc1[ni][rt][0] + b1v.x, 0.0f);
      hv[1] = (_Float16)fmaxf(acc1[ni][rt][1] + b1v.y, 0.0f);
      hv[2] = (_Float16)fmaxf(acc1[ni][rt][2] + b1v.z, 0.0f);
      hv[3] = (_Float16)fmaxf(acc1[ni][rt][3] + b1v.w, 0.0f);
      int swz = (kq2 & ~7) | ((kq2 & 7) ^ (row & 7));
      *(f16x4*)&lds_h[row * 1024 + (swz << 4) + ((quad & 1) << 3)] = hv;
    }
  }
  __syncthreads();

  f32x4 acc2[4][4];
#pragma unroll
  for (int ni = 0; ni < 4; ni++)
#pragma unroll
    for (int rt = 0; rt < 4; rt++) acc2[ni][rt] = (f32x4)(0.0f);

#pragma unroll 2
  for (int kt = 0; kt < 16; kt++) {
    f16x8 bh[4];
#pragma unroll
    for (int rt = 0; rt < 4; rt++) {
      int row = rt * 16 + l15;
      int kq = kt * 4 + quad;
      int swz = (kq & ~7) | ((kq & 7) ^ (row & 7));
      bh[rt] = *(const f16x8*)&lds_h[row * 1024 + (swz << 4)];
    }
#pragma unroll
    for (int ni = 0; ni < 4; ni++) {
      f16x8 aw = *(const f16x8*)&w2t[((w * 4 + ni) * 16 + kt) * 512 + l * 8];
#pragma unroll
      for (int rt = 0; rt < 4; rt++)
        acc2[ni][rt] = MFMA16(aw, bh[rt], acc2[ni][rt]);
    }
  }

#pragma unroll
  for (int rt = 0; rt < 4; rt++) {
    int pr = R0 + rt * 16 + l15;
    bool valid;
    if (qm) {
      valid = true;
    } else {
      int ch = pr / 5120, pos = pr - ch * 5120;
      valid = pos < 5000;
    }
    float s = 0.0f;
#pragma unroll
    for (int ni = 0; ni < 4; ni++) {
      float4 b2v = *(const float4*)&b2[ncol0 + ni * 16 + quad * 4];
      f16x4 ov;
      if (valid) {
        ov[0] = (_Float16)(acc2[ni][rt][0] + b2v.x);
        ov[1] = (_Float16)(acc2[ni][rt][1] + b2v.y);
        ov[2] = (_Float16)(acc2[ni][rt][2] + b2v.z);
        ov[3] = (_Float16)(acc2[ni][rt][3] + b2v.w);
#pragma unroll
        for (int r = 0; r < 4; r++) {
          float cv = (float)ov[r];
          s += cv * cv;
        }
      } else {
        ov[0] = (_Float16)0.0f; ov[1] = (_Float16)0.0f;
        ov[2] = (_Float16)0.0f; ov[3] = (_Float16)0.0f;
        s += 4.0f * 19.53125f;               // 1e4 / 512 per pad element
      }
      // fragment-packed store:
      // byte = (pr>>5)*32768 + (n0>>4)*1024 + ((pr&31)+32*((n0>>3)&1))*16 + (n0&7)*2
      int n0 = ncol0 + ni * 16 + quad * 4;
      size_t byteoff = (size_t)(pr >> 5) * 32768 + (size_t)(n0 >> 4) * 1024 +
                       (size_t)((pr & 31) + 32 * ((n0 >> 3) & 1)) * 16 +
                       (size_t)(n0 & 7) * 2;
      *(f16x4*)((char*)out + byteoff) = ov;
    }
    s += __shfl_xor(s, 16);
    s += __shfl_xor(s, 32);
    if (quad == 0) atomicAdd(&outsq[pr], s);
  }
}

// ---------------- fused distance + reductions (8-deep in-tile c ring)
// 1280 blocks x 512 threads (8 waves). id: xcd=id&7 (owns cols [xcd*12800,
// +12800)), by=(id>>3)&15 (64 q-rows), m=id>>7 -> col-group g=xcd*10+m
// (1280 cols = 40 tiles of 32; wave w does tiles w, w+8, ...).
// q: 64KB fragment-packed, memcpy'd to LDS; reads linear (conflict-free).
// c: fragment-packed; per-ks load = wave-uniform base + l*16 (1KB burst),
// in-tile 8-deep ring (prologue 8; ks0..23 load ks+8; ks24..31 drain --
// br never live across the epilogue, unlike R15/R16).
// dist MFMA: D[cand][qrow] (A=c, B=q) -> lane l31 = qrow, reg rr = cand,
// rr=(r&3)+8*(r>>2)+4*half. csq read per-lane (L1-hot immediates). Logits
// A-frags in registers via cvt_pkrtz + v_permlane32_swap_b32 (one wv[8],
// acc0 then acc1). Raw v_sqrt_f32. launch_bounds (512,4): 64 arch + 64 acc
// = 128 unified -> 4 waves/SIMD; LDS 2x68096 -> 2 blocks/CU -> 16 waves/CU.
__global__ __launch_bounds__(512, 4) void dist_kernel(
    const _Float16* __restrict__ q, const _Float16* __restrict__ c,
    const float* __restrict__ qsq, const float* __restrict__ csq,
    const int* __restrict__ ypad, float* __restrict__ sumexp,
    float* __restrict__ lgts_part) {
  __shared__ __align__(16) char lds_q[65536];   // 2 row-groups x 32KB packed
  __shared__ float lds_logit[640];              // 64 rows x 10 classes

  const int t = threadIdx.x, w = t >> 6, l = t & 63;
  const int l31 = l & 31, half = l >> 5;
  const int id = blockIdx.x;
  const int xcd = id & 7, by = (id >> 3) & 15, m = id >> 7;
  const int g = xcd * 10 + m;
  const int row0 = by * 64, chunk = g >> 2;   // 4 col-groups per 5120-chunk

  for (int i = t; i < 640; i += 512) lds_logit[i] = 0.0f;

  // stage q row-groups (row0>>5, +1): straight 64KB copy, fully coalesced
  {
    const char* qsrc = (const char*)q + (size_t)(row0 >> 5) * 32768;
#pragma unroll
    for (int it = 0; it < 8; it++) {
      int idx = it * 512 + t;
      *(f16x8*)&lds_q[idx * 16] = *(const f16x8*)(qsrc + (size_t)idx * 16);
    }
  }
  __syncthreads();

  const float qs0 = qsq[row0 + l31];         // qrow for acc0 lane
  const float qs1 = qsq[row0 + 32 + l31];    // qrow for acc1 lane
  float sume0 = 0.0f, sume1 = 0.0f;
  f32x16 lacc0 = (f32x16)(0.0f), lacc1 = (f32x16)(0.0f);

  for (int tile = w; tile < 40; tile += 8) {
    int col0 = g * 1280 + tile * 32;
    const char* cb = (const char*)c + (size_t)(col0 >> 5) * 32768 + l * 16;
    const float* cbase = csq + col0 + 4 * half;  // cands for this lane's half

    f32x16 acc0 = (f32x16)(0.0f), acc1 = (f32x16)(0.0f);
    f16x8 br[8];
#pragma unroll
    for (int i = 0; i < 8; i++) br[i] = *(const f16x8*)(cb + i * 1024);

#pragma unroll 8
    for (int ks = 0; ks < 24; ks++) {
      f16x8 bn = *(const f16x8*)(cb + (ks + 8) * 1024);
      f16x8 a0 = *(const f16x8*)&lds_q[ks * 1024 + l * 16];
      f16x8 a1 = *(const f16x8*)&lds_q[32768 + ks * 1024 + l * 16];
      acc0 = MFMA32(br[ks & 7], a0, acc0);   // D[cand][qrow 0..31]
      acc1 = MFMA32(br[ks & 7], a1, acc1);   // D[cand][qrow 32..63]
      br[ks & 7] = bn;
    }
#pragma unroll
    for (int ks = 24; ks < 32; ks++) {       // ring drains; no loads
      f16x8 a0 = *(const f16x8*)&lds_q[ks * 1024 + l * 16];
      f16x8 a1 = *(const f16x8*)&lds_q[32768 + ks * 1024 + l * 16];
      acc0 = MFMA32(br[ks & 7], a0, acc0);
      acc1 = MFMA32(br[ks & 7], a1, acc1);
    }

    // one-hot B-frags from ypad (class cols l31>=10 get zeros; br dead here)
    f16x8 bf0, bf1;
    {
      int base = col0 + half * 8;
      int4 ya = *(const int4*)&ypad[base];
      int4 yb = *(const int4*)&ypad[base + 4];
      int4 yc = *(const int4*)&ypad[base + 16];
      int4 yd = *(const int4*)&ypad[base + 20];
      bf0[0] = (_Float16)(ya.x == l31 ? 1.0f : 0.0f);
      bf0[1] = (_Float16)(ya.y == l31 ? 1.0f : 0.0f);
      bf0[2] = (_Float16)(ya.z == l31 ? 1.0f : 0.0f);
      bf0[3] = (_Float16)(ya.w == l31 ? 1.0f : 0.0f);
      bf0[4] = (_Float16)(yb.x == l31 ? 1.0f : 0.0f);
      bf0[5] = (_Float16)(yb.y == l31 ? 1.0f : 0.0f);
      bf0[6] = (_Float16)(yb.z == l31 ? 1.0f : 0.0f);
      bf0[7] = (_Float16)(yb.w == l31 ? 1.0f : 0.0f);
      bf1[0] = (_Float16)(yc.x == l31 ? 1.0f : 0.0f);
      bf1[1] = (_Float16)(yc.y == l31 ? 1.0f : 0.0f);
      bf1[2] = (_Float16)(yc.z == l31 ? 1.0f : 0.0f);
      bf1[3] = (_Float16)(yc.w == l31 ? 1.0f : 0.0f);
      bf1[4] = (_Float16)(yd.x == l31 ? 1.0f : 0.0f);
      bf1[5] = (_Float16)(yd.y == l31 ? 1.0f : 0.0f);
      bf1[6] = (_Float16)(yd.z == l31 ? 1.0f : 0.0f);
      bf1[7] = (_Float16)(yd.w == l31 ? 1.0f : 0.0f);
    }

    // epilogue half 0: acc0 -> ed -> wv -> PLSWAP -> logits MFMA into lacc0
    {
      unsigned wv[8];
#pragma unroll
      for (int rp = 0; rp < 8; rp++) {
        int r0 = rp * 2;
        int rrlo = (r0 & 3) + 8 * (r0 >> 2);   // compile-time per rp
        float cs0 = cbase[rrlo];
        float cs1 = cbase[rrlo + 1];
        float e00 = __expf(-__builtin_amdgcn_sqrtf(fmaxf(qs0 + cs0 - 2.0f * acc0[r0], 0.0f)));
        float e01 = __expf(-__builtin_amdgcn_sqrtf(fmaxf(qs0 + cs1 - 2.0f * acc0[r0 + 1], 0.0f)));
        sume0 += __expf(e00) + __expf(e01);    // pad cols: ed==0 -> adds 1.0
        wv[rp] = pkh(e00, e01);
      }
      PLSWAP(wv[0], wv[2]); PLSWAP(wv[1], wv[3]);
      PLSWAP(wv[4], wv[6]); PLSWAP(wv[5], wv[7]);
      lacc0 = MFMA32(mk8(wv[0], wv[1], wv[2], wv[3]), bf0, lacc0);
      lacc0 = MFMA32(mk8(wv[4], wv[5], wv[6], wv[7]), bf1, lacc0);
    }

    // epilogue half 1: acc1 -> lacc1 (reuses the wv slots)
    {
      unsigned wv[8];
#pragma unroll
      for (int rp = 0; rp < 8; rp++) {
        int r0 = rp * 2;
        int rrlo = (r0 & 3) + 8 * (r0 >> 2);
        float cs0 = cbase[rrlo];
        float cs1 = cbase[rrlo + 1];
        float e10 = __expf(-__builtin_amdgcn_sqrtf(fmaxf(qs1 + cs0 - 2.0f * acc1[r0], 0.0f)));
        float e11 = __expf(-__builtin_amdgcn_sqrtf(fmaxf(qs1 + cs1 - 2.0f * acc1[r0 + 1], 0.0f)));
        sume1 += __expf(e10) + __expf(e11);
        wv[rp] = pkh(e10, e11);
      }
      PLSWAP(wv[0], wv[2]); PLSWAP(wv[1], wv[3]);
      PLSWAP(wv[4], wv[6]); PLSWAP(wv[5], wv[7]);
      lacc1 = MFMA32(mk8(wv[0], wv[1], wv[2], wv[3]), bf0, lacc1);
      lacc1 = MFMA32(mk8(wv[4], wv[5], wv[6], wv[7]), bf1, lacc1);
    }
  }

  // flush sumexp: combine the two cand-halves of each qrow, 1 atomic per row
  sume0 += __shfl_xor(sume0, 32);
  sume1 += __shfl_xor(sume1, 32);
  if (half == 0) {
    atomicAdd(&sumexp[(row0 + l31) * 20 + chunk], sume0);
    atomicAdd(&sumexp[(row0 + 32 + l31) * 20 + chunk], sume1);
  }

  // flush logits: lacc D-layout: col=class=l31, row rr=(r&3)+8*(r>>2)+4*half
  if (l31 < 10) {
#pragma unroll
    for (int r = 0; r < 16; r++) {
      int rr = (r & 3) + 8 * (r >> 2) + 4 * half;
      atomicAdd(&lds_logit[rr * 10 + l31], lacc0[r]);
      atomicAdd(&lds_logit[(32 + rr) * 10 + l31], lacc1[r]);
    }
  }
  __syncthreads();
  float* lp = lgts_part + (size_t)xcd * 10240 + row0 * 10;
  for (int i = t; i < 640; i += 512) atomicAdd(&lp[i], lds_logit[i]);
}

// ---------------- finalize: out[i,k] = log(Σ_xcd lgts_part) - Σ_ch log(sumexp-120)
__global__ __launch_bounds__(256) void finalize_kernel(
    const float* __restrict__ lgts_part, const float* __restrict__ sumexp,
    float* __restrict__ out) {
  int i = blockIdx.x * 256 + threadIdx.x;
  if (i >= 1024) return;
  float lse = 0.0f;
#pragma unroll
  for (int ch = 0; ch < 20; ch++) lse += logf(sumexp[i * 20 + ch] - 120.0f);
#pragma unroll
  for (int k = 0; k < 10; k++) {
    float lg = 0.0f;
#pragma unroll
    for (int x = 0; x < 8; x++) lg += lgts_part[x * 10240 + i * 10 + k];
    out[i * 10 + k] = logf(lg) - lse;
  }
}

extern "C" void kernel_launch(void* const* d_in, const int* in_sizes, int n_in,
                              void* d_out, int out_size, void* d_ws, size_t ws_size,
                              hipStream_t stream) {
  const float* x_num = (const float*)d_in[0];
  const float* x_cat = (const float*)d_in[1];
  const float* cxn   = (const float*)d_in[2];
  const float* cxc   = (const float*)d_in[3];
  const int*   cy    = (const int*)d_in[4];
  const float* W1    = (const float*)d_in[5];
  const float* b1    = (const float*)d_in[6];
  const float* W2    = (const float*)d_in[7];
  const float* b2    = (const float*)d_in[8];
  float* out = (float*)d_out;

  char* ws = (char*)d_ws;
  _Float16* c    = (_Float16*)(ws + 0);           // packed 3200*32768 = 104857600
  _Float16* qe   = (_Float16*)(ws + 104857600);   // packed 32*32768  = 1048576
  _Float16* w1t  = (_Float16*)(ws + 105906176);   // packed 32*3*1KB  = 98304
  _Float16* w2t  = (_Float16*)(ws + 106004480);   // packed 32*16*1KB = 524288
  float*    csq  = (float*)(ws + 106528768);      // 102400*4     = 409600
  float*    qsq  = (float*)(ws + 106938368);      // 1024*4       = 4096
  float*    sume = (float*)(ws + 106942464);      // 1024*20*4    = 81920
  float*    lgtp = (float*)(ws + 107024384);      // 8*1024*10*4  = 327680
  int*      ypad = (int*)(ws + 107352064);        // 102400*4     = 409600

  prep_kernel<<<2420, 256, 0, stream>>>(W1, W2, cy, w1t, w2t, ypad, csq);
  encode_kernel<<<1616, 512, 0, stream>>>(cxn, cxc, x_num, x_cat, w1t, b1, w2t, b2, c, csq, qe, qsq);
  dist_kernel<<<1280, 512, 0, stream>>>(qe, c, qsq, csq, ypad, sume, lgtp);
  finalize_kernel<<<4, 256, 0, stream>>>(lgtp, sume, out);
}

// Round 17
// 326.260 us; speedup vs baseline: 1.3886x; 1.3886x over previous
//
#include <hip/hip_runtime.h>
#include <hip/hip_bf16.h>

// ModernNCA fused pipeline for MI355X (gfx950). Round 19: revert to R17, the
// verified best (347.5us).
//
// R18 post-mortem: 8-deep ring = third consecutive spill (FETCH 483MB, WRITE
// 198MB, dist 285us). br[8]=32 regs + unroll-8 bn temporaries > 64-arch cap.
// CONCLUSION (3x counter-verified): at (512,4) the 4-deep in-tile ring is the
// deepest latency-hiding structure this decomposition admits; occupancy is
// capped at 16 waves/CU by the 64-reg accumulator set. dist ~165us = floor.
//
// Padding: 5000->5120 per chunk; pad rows c=0, csq=1e4 -> d>=100 -> ed==0;
// each pad adds exp(0)=1 to chunk sumexp; finalize subtracts 120.

typedef _Float16 f16x8 __attribute__((ext_vector_type(8)));
typedef _Float16 f16x4 __attribute__((ext_vector_type(4)));
typedef __fp16 fp16x2r __attribute__((ext_vector_type(2)));  // cvt_pkrtz ret type
typedef float f32x4 __attribute__((ext_vector_type(4)));
typedef float f32x16 __attribute__((ext_vector_type(16)));

#define MFMA16(a, b, c) __builtin_amdgcn_mfma_f32_16x16x32_f16(a, b, c, 0, 0, 0)
#define MFMA32(a, b, c) __builtin_amdgcn_mfma_f32_32x32x16_f16(a, b, c, 0, 0, 0)

// pack two f32 -> one u32 of 2 f16 (RTZ)
static __device__ __forceinline__ unsigned pkh(float a, float b) {
  union { fp16x2r h; unsigned u; } x;
  x.h = __builtin_amdgcn_cvt_pkrtz(a, b);
  return x.u;
}

static __device__ __forceinline__ f16x8 mk8(unsigned a, unsigned b, unsigned c,
                                            unsigned d) {
  union { unsigned u[4]; f16x8 v; } x;
  x.u[0] = a; x.u[1] = b; x.u[2] = c; x.u[3] = d;
  return x.v;
}

// v_permlane32_swap_b32 a, b : exchanges a.hi(lanes32-63) <-> b.lo(lanes0-31)
#define PLSWAP(a, b) asm("v_permlane32_swap_b32 %0, %1" : "+v"(a), "+v"(b))

// ---------------- prep: fragment-packed W1t/W2t, padded y, zero accumulators
// Weight fragment packing: for A-frag at (n-tile nt, k-tile kt), lane
// l = quad*16 + l15 holds row nt*16+l15, cols kt*32+quad*8..+8. Stored as one
// 1KB block: halfword dst = (nt*KT+kt)*512 + l*8 + e.
__global__ __launch_bounds__(256) void prep_kernel(
    const float* __restrict__ W1, const float* __restrict__ W2,
    const int* __restrict__ y, _Float16* __restrict__ w1t,
    _Float16* __restrict__ w2t, int* __restrict__ ypad,
    float* __restrict__ zero_base) {
  int idx = blockIdx.x * 256 + threadIdx.x;
  if (idx < 49152) {                       // W1 [96,512] -> packed [32][3][1KB]
    int n = idx / 96, k = idx - n * 96;
    int nt = n >> 4, l15 = n & 15;
    int kt = k >> 5, kr = k & 31, quad = kr >> 3, e = kr & 7;
    int lane = quad * 16 + l15;
    w1t[(nt * 3 + kt) * 512 + lane * 8 + e] = (_Float16)W1[k * 512 + n];
  } else if (idx < 311296) {               // W2 [512,512] -> packed [32][16][1KB]
    int j = idx - 49152;
    int n = j / 512, k = j - n * 512;
    int nt = n >> 4, l15 = n & 15;
    int kt = k >> 5, kr = k & 31, quad = kr >> 3, e = kr & 7;
    int lane = quad * 16 + l15;
    w2t[(nt * 16 + kt) * 512 + lane * 8 + e] = (_Float16)W2[k * 512 + n];
  } else if (idx < 413696) {               // padded candidate_y
    int j = idx - 311296;
    int ch = j / 5120, pos = j - ch * 5120;
    ypad[j] = (pos < 5000) ? y[ch * 5000 + pos] : 0;
  } else if (idx < 619520) {
    // zero: csq(102400) qsq(1024) sumexp(20480) lgts_part(81920) = 205824 f32
    zero_base[idx - 413696] = 0.0f;
  }
}

// ---------------- fused 2-layer encoder: enc = relu(x@W1+b1)@W2 + b2
// One launch covers BOTH inputs: blocks [0,16) = query rows (1024, no chunk
// padding), blocks [16,1616) = candidate rows (5000->5120 chunked). Mode is
// block-uniform; each path keeps its compile-time constants.
// 512 threads / 8 waves; each wave owns 64 output cols (4 n-tiles) -> acc =
// 64 AGPR; (512,4) pins 64 arch + 64 acc = 128 unified -> 4 waves/SIMD,
// LDS 80KB -> 2 blocks/CU -> 16 waves/CU.
// Output written in MFMA-fragment-packed layout; weights read fragment-packed.
__global__ __launch_bounds__(512, 4) void encode_kernel(
    const float* __restrict__ xn_c, const float* __restrict__ xc_c,
    const float* __restrict__ xn_q, const float* __restrict__ xc_q,
    const _Float16* __restrict__ w1t, const float* __restrict__ b1,
    const _Float16* __restrict__ w2t, const float* __restrict__ b2,
    _Float16* __restrict__ out_c, float* __restrict__ csq,
    _Float16* __restrict__ out_q, float* __restrict__ qsq) {
  __shared__ __align__(16) char lds_x[16384];  // 64 rows x 16 units(16B) swz
  __shared__ __align__(16) char lds_h[65536];  // 64 rows x 64 units(16B) swz

  const int t = threadIdx.x;
  const bool qm = blockIdx.x < 16;
  const int R0 = (qm ? blockIdx.x : blockIdx.x - 16) * 64;
  const float* xn = qm ? xn_q : xn_c;
  const float* xc = qm ? xc_q : xc_c;
  _Float16* out = qm ? out_q : out_c;
  float* outsq = qm ? qsq : csq;

  const int w = t >> 6, l = t & 63;          // w in [0,8)
  const int l15 = l & 15, quad = l >> 4;
  const int ncol0 = w * 64;                  // 64 cols per wave

#pragma unroll
  for (int it = 0; it < 2; it++) {
    int idx = it * 512 + t;
    int row = idx >> 4, kq = idx & 15;
    int pr = R0 + row;
    int orig;
    bool rowvalid;
    if (qm) {
      orig = pr; rowvalid = true;
    } else {
      int ch = pr / 5120, pos = pr - ch * 5120;
      rowvalid = pos < 5000;
      orig = ch * 5000 + pos;
    }
    float v[8] = {0, 0, 0, 0, 0, 0, 0, 0};
    if (rowvalid && kq < 12) {
      float4 f0, f1;
      if (kq < 8) {
        f0 = *(const float4*)&xn[orig * 64 + kq * 8];
        f1 = *(const float4*)&xn[orig * 64 + kq * 8 + 4];
      } else {
        f0 = *(const float4*)&xc[orig * 32 + (kq - 8) * 8];
        f1 = *(const float4*)&xc[orig * 32 + (kq - 8) * 8 + 4];
      }
      v[0] = f0.x; v[1] = f0.y; v[2] = f0.z; v[3] = f0.w;
      v[4] = f1.x; v[5] = f1.y; v[6] = f1.z; v[7] = f1.w;
    }
    f16x8 hv;
#pragma unroll
    for (int j = 0; j < 8; j++) hv[j] = (_Float16)v[j];
    *(f16x8*)&lds_x[row * 256 + (((kq ^ (row & 7)) & 15) << 4)] = hv;
  }
  __syncthreads();

  f32x4 acc1[4][4];
#pragma unroll
  for (int ni = 0; ni < 4; ni++)
#pragma unroll
    for (int rt = 0; rt < 4; rt++) acc1[ni][rt] = (f32x4)(0.0f);

#pragma unroll
  for (int kt = 0; kt < 3; kt++) {
    f16x8 bx[4];
#pragma unroll
    for (int rt = 0; rt < 4; rt++) {
      int row = rt * 16 + l15;
      int kq = kt * 4 + quad;
      bx[rt] = *(const f16x8*)&lds_x[row * 256 + (((kq ^ (row & 7)) & 15) << 4)];
    }
#pragma unroll
    for (int ni = 0; ni < 4; ni++) {
      f16x8 aw = *(const f16x8*)&w1t[((w * 4 + ni) * 3 + kt) * 512 + l * 8];
#pragma unroll
      for (int rt = 0; rt < 4; rt++) acc1[ni][rt] = MFMA16(aw, bx[rt], acc1[ni][rt]);
    }
  }

#pragma unroll
  for (int ni = 0; ni < 4; ni++) {
    float4 b1v = *(const float4*)&b1[ncol0 + ni * 16 + quad * 4];
    int kq2 = (ncol0 >> 3) + ni * 2 + (quad >> 1);
#pragma unroll
    for (int rt = 0; rt < 4; rt++) {
      int row = rt * 16 + l15;
      f16x4 hv;
      hv[0] = (_Float16)fmaxf(acc1[ni][rt][0] + b1v.x, 0.0f);
      hv[1] = (_Float16)fmaxf(acc1[ni][rt][1] + b1v.y, 0.0f);
      hv[2] = (_Float16)fmaxf(acc1[ni][rt][2] + b1v.z, 0.0f);
      hv[3] = (_Float16)fmaxf(acc1[ni][rt][3] + b1v.w, 0.0f);
      int swz = (kq2 & ~7) | ((kq2 & 7) ^ (row & 7));
      *(f16x4*)&lds_h[row * 1024 + (swz << 4) + ((quad & 1) << 3)] = hv;
    }
  }
  __syncthreads();

  f32x4 acc2[4][4];
#pragma unroll
  for (int ni = 0; ni < 4; ni++)
#pragma unroll
    for (int rt = 0; rt < 4; rt++) acc2[ni][rt] = (f32x4)(0.0f);

#pragma unroll 2
  for (int kt = 0; kt < 16; kt++) {
    f16x8 bh[4];
#pragma unroll
    for (int rt = 0; rt < 4; rt++) {
      int row = rt * 16 + l15;
      int kq = kt * 4 + quad;
      int swz = (kq & ~7) | ((kq & 7) ^ (row & 7));
      bh[rt] = *(const f16x8*)&lds_h[row * 1024 + (swz << 4)];
    }
#pragma unroll
    for (int ni = 0; ni < 4; ni++) {
      f16x8 aw = *(const f16x8*)&w2t[((w * 4 + ni) * 16 + kt) * 512 + l * 8];
#pragma unroll
      for (int rt = 0; rt < 4; rt++)
        acc2[ni][rt] = MFMA16(aw, bh[rt], acc2[ni][rt]);
    }
  }

#pragma unroll
  for (int rt = 0; rt < 4; rt++) {
    int pr = R0 + rt * 16 + l15;
    bool valid;
    if (qm) {
      valid = true;
    } else {
      int ch = pr / 5120, pos = pr - ch * 5120;
      valid = pos < 5000;
    }
    float s = 0.0f;
#pragma unroll
    for (int ni = 0; ni < 4; ni++) {
      float4 b2v = *(const float4*)&b2[ncol0 + ni * 16 + quad * 4];
      f16x4 ov;
      if (valid) {
        ov[0] = (_Float16)(acc2[ni][rt][0] + b2v.x);
        ov[1] = (_Float16)(acc2[ni][rt][1] + b2v.y);
        ov[2] = (_Float16)(acc2[ni][rt][2] + b2v.z);
        ov[3] = (_Float16)(acc2[ni][rt][3] + b2v.w);
#pragma unroll
        for (int r = 0; r < 4; r++) {
          float cv = (float)ov[r];
          s += cv * cv;
        }
      } else {
        ov[0] = (_Float16)0.0f; ov[1] = (_Float16)0.0f;
        ov[2] = (_Float16)0.0f; ov[3] = (_Float16)0.0f;
        s += 4.0f * 19.53125f;               // 1e4 / 512 per pad element
      }
      // fragment-packed store:
      // byte = (pr>>5)*32768 + (n0>>4)*1024 + ((pr&31)+32*((n0>>3)&1))*16 + (n0&7)*2
      int n0 = ncol0 + ni * 16 + quad * 4;
      size_t byteoff = (size_t)(pr >> 5) * 32768 + (size_t)(n0 >> 4) * 1024 +
                       (size_t)((pr & 31) + 32 * ((n0 >> 3) & 1)) * 16 +
                       (size_t)(n0 & 7) * 2;
      *(f16x4*)((char*)out + byteoff) = ov;
    }
    s += __shfl_xor(s, 16);
    s += __shfl_xor(s, 32);
    if (quad == 0) atomicAdd(&outsq[pr], s);
  }
}

// ---------------- fused distance + reductions (R14 verified version)
// 1280 blocks x 512 threads (8 waves). id: xcd=id&7 (owns cols [xcd*12800,
// +12800)), by=(id>>3)&15 (64 q-rows), m=id>>7 -> col-group g=xcd*10+m
// (1280 cols = 40 tiles of 32; wave w does tiles w, w+8, ...).
// q: 64KB fragment-packed, memcpy'd to LDS; reads linear (conflict-free).
// c: fragment-packed; per-ks load = wave-uniform base + l*16 (1KB burst),
// in-tile 4-deep ring (the max depth that fits the 64-arch cap; 8-deep and
// cross-tile variants all spilled). dist MFMA: D[cand][qrow] (A=c, B=q) ->
// lane l31 = qrow, reg rr = cand, rr=(r&3)+8*(r>>2)+4*half. csq read per-lane
// (L1-hot immediates). Logits A-frags in registers via cvt_pkrtz +
// v_permlane32_swap_b32 (one wv[8], acc0 then acc1). Raw v_sqrt_f32.
// launch_bounds (512,4): 64 arch + 64 acc = 128 unified -> 4 waves/SIMD;
// LDS 2x68096 -> 2 blocks/CU -> 16 waves/CU.
__global__ __launch_bounds__(512, 4) void dist_kernel(
    const _Float16* __restrict__ q, const _Float16* __restrict__ c,
    const float* __restrict__ qsq, const float* __restrict__ csq,
    const int* __restrict__ ypad, float* __restrict__ sumexp,
    float* __restrict__ lgts_part) {
  __shared__ __align__(16) char lds_q[65536];   // 2 row-groups x 32KB packed
  __shared__ float lds_logit[640];              // 64 rows x 10 classes

  const int t = threadIdx.x, w = t >> 6, l = t & 63;
  const int l31 = l & 31, half = l >> 5;
  const int id = blockIdx.x;
  const int xcd = id & 7, by = (id >> 3) & 15, m = id >> 7;
  const int g = xcd * 10 + m;
  const int row0 = by * 64, chunk = g >> 2;   // 4 col-groups per 5120-chunk

  for (int i = t; i < 640; i += 512) lds_logit[i] = 0.0f;

  // stage q row-groups (row0>>5, +1): straight 64KB copy, fully coalesced
  {
    const char* qsrc = (const char*)q + (size_t)(row0 >> 5) * 32768;
#pragma unroll
    for (int it = 0; it < 8; it++) {
      int idx = it * 512 + t;
      *(f16x8*)&lds_q[idx * 16] = *(const f16x8*)(qsrc + (size_t)idx * 16);
    }
  }
  __syncthreads();

  const float qs0 = qsq[row0 + l31];         // qrow for acc0 lane
  const float qs1 = qsq[row0 + 32 + l31];    // qrow for acc1 lane
  float sume0 = 0.0f, sume1 = 0.0f;
  f32x16 lacc0 = (f32x16)(0.0f), lacc1 = (f32x16)(0.0f);

  for (int tile = w; tile < 40; tile += 8) {
    int col0 = g * 1280 + tile * 32;
    const char* cb = (const char*)c + (size_t)(col0 >> 5) * 32768 + l * 16;
    const float* cbase = csq + col0 + 4 * half;  // cands for this lane's half

    f32x16 acc0 = (f32x16)(0.0f), acc1 = (f32x16)(0.0f);
    f16x8 br[4];
#pragma unroll
    for (int i = 0; i < 4; i++) br[i] = *(const f16x8*)(cb + i * 1024);

#pragma unroll 4
    for (int ks = 0; ks < 32; ks++) {
      f16x8 bn = *(const f16x8*)(cb + ((ks + 4) & 31) * 1024);
      f16x8 a0 = *(const f16x8*)&lds_q[ks * 1024 + l * 16];
      f16x8 a1 = *(const f16x8*)&lds_q[32768 + ks * 1024 + l * 16];
      acc0 = MFMA32(br[ks & 3], a0, acc0);   // D[cand][qrow 0..31]
      acc1 = MFMA32(br[ks & 3], a1, acc1);   // D[cand][qrow 32..63]
      br[ks & 3] = bn;
    }

    // one-hot B-frags from ypad (class cols l31>=10 get zeros)
    f16x8 bf0, bf1;
    {
      int base = col0 + half * 8;
      int4 ya = *(const int4*)&ypad[base];
      int4 yb = *(const int4*)&ypad[base + 4];
      int4 yc = *(const int4*)&ypad[base + 16];
      int4 yd = *(const int4*)&ypad[base + 20];
      bf0[0] = (_Float16)(ya.x == l31 ? 1.0f : 0.0f);
      bf0[1] = (_Float16)(ya.y == l31 ? 1.0f : 0.0f);
      bf0[2] = (_Float16)(ya.z == l31 ? 1.0f : 0.0f);
      bf0[3] = (_Float16)(ya.w == l31 ? 1.0f : 0.0f);
      bf0[4] = (_Float16)(yb.x == l31 ? 1.0f : 0.0f);
      bf0[5] = (_Float16)(yb.y == l31 ? 1.0f : 0.0f);
      bf0[6] = (_Float16)(yb.z == l31 ? 1.0f : 0.0f);
      bf0[7] = (_Float16)(yb.w == l31 ? 1.0f : 0.0f);
      bf1[0] = (_Float16)(yc.x == l31 ? 1.0f : 0.0f);
      bf1[1] = (_Float16)(yc.y == l31 ? 1.0f : 0.0f);
      bf1[2] = (_Float16)(yc.z == l31 ? 1.0f : 0.0f);
      bf1[3] = (_Float16)(yc.w == l31 ? 1.0f : 0.0f);
      bf1[4] = (_Float16)(yd.x == l31 ? 1.0f : 0.0f);
      bf1[5] = (_Float16)(yd.y == l31 ? 1.0f : 0.0f);
      bf1[6] = (_Float16)(yd.z == l31 ? 1.0f : 0.0f);
      bf1[7] = (_Float16)(yd.w == l31 ? 1.0f : 0.0f);
    }

    // epilogue half 0: acc0 -> ed -> wv -> PLSWAP -> logits MFMA into lacc0
    {
      unsigned wv[8];
#pragma unroll
      for (int rp = 0; rp < 8; rp++) {
        int r0 = rp * 2;
        int rrlo = (r0 & 3) + 8 * (r0 >> 2);   // compile-time per rp
        float cs0 = cbase[rrlo];
        float cs1 = cbase[rrlo + 1];
        float e00 = __expf(-__builtin_amdgcn_sqrtf(fmaxf(qs0 + cs0 - 2.0f * acc0[r0], 0.0f)));
        float e01 = __expf(-__builtin_amdgcn_sqrtf(fmaxf(qs0 + cs1 - 2.0f * acc0[r0 + 1], 0.0f)));
        sume0 += __expf(e00) + __expf(e01);    // pad cols: ed==0 -> adds 1.0
        wv[rp] = pkh(e00, e01);
      }
      PLSWAP(wv[0], wv[2]); PLSWAP(wv[1], wv[3]);
      PLSWAP(wv[4], wv[6]); PLSWAP(wv[5], wv[7]);
      lacc0 = MFMA32(mk8(wv[0], wv[1], wv[2], wv[3]), bf0, lacc0);
      lacc0 = MFMA32(mk8(wv[4], wv[5], wv[6], wv[7]), bf1, lacc0);
    }

    // epilogue half 1: acc1 -> lacc1 (reuses the wv slots)
    {
      unsigned wv[8];
#pragma unroll
      for (int rp = 0; rp < 8; rp++) {
        int r0 = rp * 2;
        int rrlo = (r0 & 3) + 8 * (r0 >> 2);
        float cs0 = cbase[rrlo];
        float cs1 = cbase[rrlo + 1];
        float e10 = __expf(-__builtin_amdgcn_sqrtf(fmaxf(qs1 + cs0 - 2.0f * acc1[r0], 0.0f)));
        float e11 = __expf(-__builtin_amdgcn_sqrtf(fmaxf(qs1 + cs1 - 2.0f * acc1[r0 + 1], 0.0f)));
        sume1 += __expf(e10) + __expf(e11);
        wv[rp] = pkh(e10, e11);
      }
      PLSWAP(wv[0], wv[2]); PLSWAP(wv[1], wv[3]);
      PLSWAP(wv[4], wv[6]); PLSWAP(wv[5], wv[7]);
      lacc1 = MFMA32(mk8(wv[0], wv[1], wv[2], wv[3]), bf0, lacc1);
      lacc1 = MFMA32(mk8(wv[4], wv[5], wv[6], wv[7]), bf1, lacc1);
    }
  }

  // flush sumexp: combine the two cand-halves of each qrow, 1 atomic per row
  sume0 += __shfl_xor(sume0, 32);
  sume1 += __shfl_xor(sume1, 32);
  if (half == 0) {
    atomicAdd(&sumexp[(row0 + l31) * 20 + chunk], sume0);
    atomicAdd(&sumexp[(row0 + 32 + l31) * 20 + chunk], sume1);
  }

  // flush logits: lacc D-layout: col=class=l31, row rr=(r&3)+8*(r>>2)+4*half
  if (l31 < 10) {
#pragma unroll
    for (int r = 0; r < 16; r++) {
      int rr = (r & 3) + 8 * (r >> 2) + 4 * half;
      atomicAdd(&lds_logit[rr * 10 + l31], lacc0[r]);
      atomicAdd(&lds_logit[(32 + rr) * 10 + l31], lacc1[r]);
    }
  }
  __syncthreads();
  float* lp = lgts_part + (size_t)xcd * 10240 + row0 * 10;
  for (int i = t; i < 640; i += 512) atomicAdd(&lp[i], lds_logit[i]);
}

// ---------------- finalize: out[i,k] = log(Σ_xcd lgts_part) - Σ_ch log(sumexp-120)
__global__ __launch_bounds__(256) void finalize_kernel(
    const float* __restrict__ lgts_part, const float* __restrict__ sumexp,
    float* __restrict__ out) {
  int i = blockIdx.x * 256 + threadIdx.x;
  if (i >= 1024) return;
  float lse = 0.0f;
#pragma unroll
  for (int ch = 0; ch < 20; ch++) lse += logf(sumexp[i * 20 + ch] - 120.0f);
#pragma unroll
  for (int k = 0; k < 10; k++) {
    float lg = 0.0f;
#pragma unroll
    for (int x = 0; x < 8; x++) lg += lgts_part[x * 10240 + i * 10 + k];
    out[i * 10 + k] = logf(lg) - lse;
  }
}

extern "C" void kernel_launch(void* const* d_in, const int* in_sizes, int n_in,
                              void* d_out, int out_size, void* d_ws, size_t ws_size,
                              hipStream_t stream) {
  const float* x_num = (const float*)d_in[0];
  const float* x_cat = (const float*)d_in[1];
  const float* cxn   = (const float*)d_in[2];
  const float* cxc   = (const float*)d_in[3];
  const int*   cy    = (const int*)d_in[4];
  const float* W1    = (const float*)d_in[5];
  const float* b1    = (const float*)d_in[6];
  const float* W2    = (const float*)d_in[7];
  const float* b2    = (const float*)d_in[8];
  float* out = (float*)d_out;

  char* ws = (char*)d_ws;
  _Float16* c    = (_Float16*)(ws + 0);           // packed 3200*32768 = 104857600
  _Float16* qe   = (_Float16*)(ws + 104857600);   // packed 32*32768  = 1048576
  _Float16* w1t  = (_Float16*)(ws + 105906176);   // packed 32*3*1KB  = 98304
  _Float16* w2t  = (_Float16*)(ws + 106004480);   // packed 32*16*1KB = 524288
  float*    csq  = (float*)(ws + 106528768);      // 102400*4     = 409600
  float*    qsq  = (float*)(ws + 106938368);      // 1024*4       = 4096
  float*    sume = (float*)(ws + 106942464);      // 1024*20*4    = 81920
  float*    lgtp = (float*)(ws + 107024384);      // 8*1024*10*4  = 327680
  int*      ypad = (int*)(ws + 107352064);        // 102400*4     = 409600

  prep_kernel<<<2420, 256, 0, stream>>>(W1, W2, cy, w1t, w2t, ypad, csq);
  encode_kernel<<<1616, 512, 0, stream>>>(cxn, cxc, x_num, x_cat, w1t, b1, w2t, b2, c, csq, qe, qsq);
  dist_kernel<<<1280, 512, 0, stream>>>(qe, c, qsq, csq, ypad, sume, lgtp);
  finalize_kernel<<<4, 256, 0, stream>>>(lgtp, sume, out);
}